// Round 1
// baseline (516.435 us; speedup 1.0000x reference)
//
#include <hip/hip_runtime.h>
#include <hip/hip_bf16.h>

// QuantizedLinear: out[M,O] = x[M,K] @ W[O,K]^T + bias, W = 4-bit group-quant (G=64)
// M=8192, O=4096, K=4096. bf16 MFMA 16x16x32, 128x128 tile, BK=64 (1 group/K-tile).

typedef short short8 __attribute__((ext_vector_type(8)));
typedef float float4v __attribute__((ext_vector_type(4)));
typedef int int4v __attribute__((ext_vector_type(4)));

#define M_TOTAL 8192
#define N_OUT 4096
#define K_IN 4096
#define BM 128
#define BN 128
#define BK 64
#define NT (K_IN / BK) // 64 K-tiles

// RTNE float->bf16 (inputs are finite normals; no NaN handling needed)
__device__ __forceinline__ short f2bf(float f) {
  unsigned int u = __builtin_bit_cast(unsigned int, f);
  unsigned int r = (u + 0x7fffu + ((u >> 16) & 1u)) >> 16;
  return (short)(unsigned short)r;
}

__global__ __launch_bounds__(256, 2)
void qlin_kernel(const float* __restrict__ x,
                 const int* __restrict__ wp,
                 const float* __restrict__ wsc,
                 const float* __restrict__ wzr,
                 const float* __restrict__ bias,
                 float* __restrict__ out) {
  // LDS tiles: [rows][64 bf16] = 128 B/row, XOR-swizzled (byte ^= (row&7)<<4)
  __shared__ __align__(16) char sA[BM * 128]; // 16 KB
  __shared__ __align__(16) char sB[BN * 128]; // 16 KB

  const int tid  = threadIdx.x;
  const int lane = tid & 63;
  const int wid  = tid >> 6;
  const int wm   = wid >> 1; // wave row 0..1
  const int wo   = wid & 1;  // wave col 0..1

  const int m0 = blockIdx.y * BM;
  const int o0 = blockIdx.x * BN;

  // ---- staging registers ----
  float4v av[8]; // A: 4 chunks x 2 float4 (32 floats)
  int4v bv[4];   // B: 16 packed int32 (one byte each -> 2 nibbles)
  float bs, bz;  // per-thread group scale/zero (thread owns half of one group row)

  const int br = tid >> 1;    // B o-row within tile (0..127)
  const int bh = tid & 1;     // half of the 64-wide group

  // ---- prologue: load tile 0 ----
  {
    const int t = 0;
#pragma unroll
    for (int q = 0; q < 4; ++q) {
      int c = q * 256 + tid;
      int row = c >> 3, cc = c & 7;
      const float* p = x + (size_t)(m0 + row) * K_IN + t * BK + cc * 8;
      av[2 * q]     = *reinterpret_cast<const float4v*>(p);
      av[2 * q + 1] = *reinterpret_cast<const float4v*>(p + 4);
    }
    const int* p = wp + ((size_t)(o0 + br) * 64 + t) * 32 + bh * 16;
#pragma unroll
    for (int q = 0; q < 4; ++q) bv[q] = *reinterpret_cast<const int4v*>(p + q * 4);
    bs = wsc[(o0 + br) * 64 + t];
    bz = wzr[(o0 + br) * 64 + t];
  }

  float4v acc[4][4];
#pragma unroll
  for (int i = 0; i < 4; ++i)
#pragma unroll
    for (int j = 0; j < 4; ++j)
      acc[i][j] = (float4v){0.f, 0.f, 0.f, 0.f};

  for (int t = 0; t < NT; ++t) {
    __syncthreads(); // previous compute done reading LDS

    // ---- store A tile (f32 -> bf16, swizzled) ----
#pragma unroll
    for (int q = 0; q < 4; ++q) {
      int c = q * 256 + tid;
      int row = c >> 3, cc = c & 7;
      short8 v;
      float4v f0 = av[2 * q], f1 = av[2 * q + 1];
#pragma unroll
      for (int e = 0; e < 4; ++e) v[e] = f2bf(f0[e]);
#pragma unroll
      for (int e = 0; e < 4; ++e) v[4 + e] = f2bf(f1[e]);
      int off = (row * 128 + cc * 16) ^ ((row & 7) << 4);
      *reinterpret_cast<short8*>(&sA[off]) = v;
    }
    // ---- store B tile (dequant nibbles -> bf16, swizzled) ----
#pragma unroll
    for (int u = 0; u < 4; ++u) {
      short8 v;
#pragma unroll
      for (int e = 0; e < 4; ++e) {
        int b = bv[u][e];
        float lo = (float)(b & 15) * bs + bz;
        float hi = (float)((b >> 4) & 15) * bs + bz;
        v[2 * e]     = f2bf(lo);
        v[2 * e + 1] = f2bf(hi);
      }
      int off = (br * 128 + bh * 64 + u * 16) ^ ((br & 7) << 4);
      *reinterpret_cast<short8*>(&sB[off]) = v;
    }

    __syncthreads(); // LDS tile ready

    // ---- prefetch next tile into regs (in flight during compute) ----
    if (t + 1 < NT) {
      const int tn = t + 1;
#pragma unroll
      for (int q = 0; q < 4; ++q) {
        int c = q * 256 + tid;
        int row = c >> 3, cc = c & 7;
        const float* p = x + (size_t)(m0 + row) * K_IN + tn * BK + cc * 8;
        av[2 * q]     = *reinterpret_cast<const float4v*>(p);
        av[2 * q + 1] = *reinterpret_cast<const float4v*>(p + 4);
      }
      const int* p = wp + ((size_t)(o0 + br) * 64 + tn) * 32 + bh * 16;
#pragma unroll
      for (int q = 0; q < 4; ++q) bv[q] = *reinterpret_cast<const int4v*>(p + q * 4);
      bs = wsc[(o0 + br) * 64 + tn];
      bz = wzr[(o0 + br) * 64 + tn];
    }

    // ---- compute: 2 K-steps x 16 MFMA ----
#pragma unroll
    for (int ks = 0; ks < 2; ++ks) {
      short8 af[4], bf[4];
      const int kb = ks * 64 + (lane >> 4) * 16; // byte offset of this lane's 8 bf16
#pragma unroll
      for (int i = 0; i < 4; ++i) {
        int row = wm * 64 + i * 16 + (lane & 15);
        int off = (row * 128 + kb) ^ ((row & 7) << 4);
        af[i] = *reinterpret_cast<const short8*>(&sA[off]);
      }
#pragma unroll
      for (int j = 0; j < 4; ++j) {
        int row = wo * 64 + j * 16 + (lane & 15);
        int off = (row * 128 + kb) ^ ((row & 7) << 4);
        bf[j] = *reinterpret_cast<const short8*>(&sB[off]);
      }
#pragma unroll
      for (int i = 0; i < 4; ++i)
#pragma unroll
        for (int j = 0; j < 4; ++j)
          acc[i][j] = __builtin_amdgcn_mfma_f32_16x16x32_bf16(af[i], bf[j], acc[i][j], 0, 0, 0);
    }
  }

  // ---- epilogue: C/D layout col=lane&15, row=(lane>>4)*4+reg ----
#pragma unroll
  for (int j = 0; j < 4; ++j) {
    int og = o0 + wo * 64 + j * 16 + (lane & 15);
    float bb = bias[og];
#pragma unroll
    for (int i = 0; i < 4; ++i) {
      int mg = m0 + wm * 64 + i * 16 + (lane >> 4) * 4;
#pragma unroll
      for (int r = 0; r < 4; ++r)
        out[(size_t)(mg + r) * N_OUT + og] = acc[i][j][r] + bb;
    }
  }
}

extern "C" void kernel_launch(void* const* d_in, const int* in_sizes, int n_in,
                              void* d_out, int out_size, void* d_ws, size_t ws_size,
                              hipStream_t stream) {
  const float* x    = (const float*)d_in[0];
  const int* wp     = (const int*)d_in[1];
  const float* wsc  = (const float*)d_in[2];
  const float* wzr  = (const float*)d_in[3];
  const float* bias = (const float*)d_in[4];
  float* out = (float*)d_out;

  dim3 grid(N_OUT / BN, M_TOTAL / BM); // (32, 64): consecutive blocks share A tile
  qlin_kernel<<<grid, dim3(256), 0, stream>>>(x, wp, wsc, wzr, bias, out);
}

// Round 2
// 335.768 us; speedup vs baseline: 1.5381x; 1.5381x over previous
//
#include <hip/hip_runtime.h>
#include <hip/hip_bf16.h>

// QuantizedLinear: out[M,O] = x[M,K] @ W[O,K]^T + bias, W 4-bit group-quant (G=64)
// M=8192, O=4096, K=4096.
// Round 2: split into (1) x f32->bf16 prepass, (2) W dequant->bf16 prepass,
// (3) pure bf16 MFMA GEMM with global_load_lds width-16 staging (m97 structure).

typedef short short8 __attribute__((ext_vector_type(8)));
typedef float float4v __attribute__((ext_vector_type(4)));
typedef int int4v __attribute__((ext_vector_type(4)));

#define M_TOTAL 8192
#define N_OUT 4096
#define K_IN 4096
#define BM 128
#define BN 128
#define BK 64
#define NT (K_IN / BK)

// RTNE float->bf16
__device__ __forceinline__ short f2bf(float f) {
  unsigned int u = __builtin_bit_cast(unsigned int, f);
  unsigned int r = (u + 0x7fffu + ((u >> 16) & 1u)) >> 16;
  return (short)(unsigned short)r;
}

__device__ __forceinline__ void gload_lds16(const void* g, void* l) {
  __builtin_amdgcn_global_load_lds(
      (const __attribute__((address_space(1))) void*)g,
      (__attribute__((address_space(3))) void*)l, 16, 0, 0);
}

// ---------------- prepass 1: x f32 -> bf16 ----------------
__global__ __launch_bounds__(256)
void cvt_x_kernel(const float* __restrict__ x, short* __restrict__ xb, int n8) {
  int i = blockIdx.x * blockDim.x + threadIdx.x;
  int stride = gridDim.x * blockDim.x;
  for (; i < n8; i += stride) {
    const float* p = x + (size_t)i * 8;
    float4v f0 = *reinterpret_cast<const float4v*>(p);
    float4v f1 = *reinterpret_cast<const float4v*>(p + 4);
    short8 v;
#pragma unroll
    for (int e = 0; e < 4; ++e) { v[e] = f2bf(f0[e]); v[4 + e] = f2bf(f1[e]); }
    *reinterpret_cast<short8*>(xb + (size_t)i * 8) = v;
  }
}

// ---------------- prepass 2: W 4-bit -> bf16 [O][K] ----------------
// thread t handles half a group: 16 packed int32 -> 32 bf16; out offset = t*32 (linear)
__global__ __launch_bounds__(256)
void deq_w_kernel(const int* __restrict__ wp, const float* __restrict__ wsc,
                  const float* __restrict__ wzr, short* __restrict__ wb) {
  int t = blockIdx.x * blockDim.x + threadIdx.x; // 0..524287
  int g = t >> 1, h = t & 1;
  float s = wsc[g], z = wzr[g];
  const int* p = wp + (size_t)g * 32 + h * 16;
  int4v b[4];
#pragma unroll
  for (int u = 0; u < 4; ++u) b[u] = *reinterpret_cast<const int4v*>(p + u * 4);
  short* o = wb + (size_t)t * 32;
#pragma unroll
  for (int u = 0; u < 4; ++u) {
    short8 v;
#pragma unroll
    for (int e = 0; e < 4; ++e) {
      int bb = b[u][e];
      v[2 * e]     = f2bf((float)(bb & 15) * s + z);
      v[2 * e + 1] = f2bf((float)((bb >> 4) & 15) * s + z);
    }
    *reinterpret_cast<short8*>(o + u * 8) = v;
  }
}

// ---------------- main GEMM: bf16 x bf16^T -> f32 ----------------
__global__ __launch_bounds__(256, 2)
void qgemm_kernel(const short* __restrict__ A, const short* __restrict__ B,
                  const float* __restrict__ bias, float* __restrict__ out) {
  __shared__ __align__(16) short sA[BM * BK]; // 16 KB, [128 rows][64 bf16] linear
  __shared__ __align__(16) short sB[BN * BK]; // 16 KB

  const int tid  = threadIdx.x;
  const int lane = tid & 63;
  const int wid  = tid >> 6;
  const int wm   = wid >> 1;
  const int wo   = wid & 1;

  const int m0 = blockIdx.y * BM;
  const int o0 = blockIdx.x * BN;

  // staging geometry: chunk c = wid*4+q covers LDS bytes [c*1024, c*1024+1024)
  // lane l -> row c*8 + (l>>3), col (l&7)*8 (bf16)
  const int srow = (lane >> 3);      // 0..7 within chunk
  const int scol = (lane & 7) * 8;   // bf16 col

  float4v acc[4][4];
#pragma unroll
  for (int i = 0; i < 4; ++i)
#pragma unroll
    for (int j = 0; j < 4; ++j)
      acc[i][j] = (float4v){0.f, 0.f, 0.f, 0.f};

  for (int t = 0; t < NT; ++t) {
    // ---- stage tile t via global_load_lds (no VALU data path) ----
#pragma unroll
    for (int q = 0; q < 4; ++q) {
      int c = wid * 4 + q;           // 0..15
      int row = c * 8 + srow;        // 0..127
      const short* gA = A + (size_t)(m0 + row) * K_IN + t * BK + scol;
      const short* gB = B + (size_t)(o0 + row) * K_IN + t * BK + scol;
      gload_lds16(gA, &sA[c * 512 + lane * 8]);
      gload_lds16(gB, &sB[c * 512 + lane * 8]);
    }
    __syncthreads(); // compiler emits vmcnt(0) drain + barrier

    // ---- compute: 2 K-steps x 16 MFMA ----
#pragma unroll
    for (int ks = 0; ks < 2; ++ks) {
      short8 af[4], bf[4];
      const int kOff = ks * 32 + (lane >> 4) * 8; // shorts within row
#pragma unroll
      for (int i = 0; i < 4; ++i)
        af[i] = *reinterpret_cast<const short8*>(&sA[(wm * 64 + i * 16 + (lane & 15)) * BK + kOff]);
#pragma unroll
      for (int j = 0; j < 4; ++j)
        bf[j] = *reinterpret_cast<const short8*>(&sB[(wo * 64 + j * 16 + (lane & 15)) * BK + kOff]);
#pragma unroll
      for (int i = 0; i < 4; ++i)
#pragma unroll
        for (int j = 0; j < 4; ++j)
          acc[i][j] = __builtin_amdgcn_mfma_f32_16x16x32_bf16(af[i], bf[j], acc[i][j], 0, 0, 0);
    }
    __syncthreads(); // compute done before next stage overwrites
  }

  // ---- epilogue: C/D layout col=lane&15, row=(lane>>4)*4+reg ----
#pragma unroll
  for (int j = 0; j < 4; ++j) {
    int og = o0 + wo * 64 + j * 16 + (lane & 15);
    float bb = bias[og];
#pragma unroll
    for (int i = 0; i < 4; ++i) {
      int mg = m0 + wm * 64 + i * 16 + (lane >> 4) * 4;
#pragma unroll
      for (int r = 0; r < 4; ++r)
        out[(size_t)(mg + r) * N_OUT + og] = acc[i][j][r] + bb;
    }
  }
}

// ---------------- fallback: round-1 fused kernel (if ws too small) ----------------
__global__ __launch_bounds__(256, 2)
void qlin_fused_kernel(const float* __restrict__ x,
                       const int* __restrict__ wp,
                       const float* __restrict__ wsc,
                       const float* __restrict__ wzr,
                       const float* __restrict__ bias,
                       float* __restrict__ out) {
  __shared__ __align__(16) char sA[BM * 128];
  __shared__ __align__(16) char sB[BN * 128];
  const int tid = threadIdx.x, lane = tid & 63, wid = tid >> 6;
  const int wm = wid >> 1, wo = wid & 1;
  const int m0 = blockIdx.y * BM, o0 = blockIdx.x * BN;
  float4v av[8]; int4v bv[4]; float bs, bz;
  const int br = tid >> 1, bh = tid & 1;
  {
#pragma unroll
    for (int q = 0; q < 4; ++q) {
      int c = q * 256 + tid; int row = c >> 3, cc = c & 7;
      const float* p = x + (size_t)(m0 + row) * K_IN + cc * 8;
      av[2 * q] = *reinterpret_cast<const float4v*>(p);
      av[2 * q + 1] = *reinterpret_cast<const float4v*>(p + 4);
    }
    const int* p = wp + ((size_t)(o0 + br) * 64) * 32 + bh * 16;
#pragma unroll
    for (int q = 0; q < 4; ++q) bv[q] = *reinterpret_cast<const int4v*>(p + q * 4);
    bs = wsc[(o0 + br) * 64]; bz = wzr[(o0 + br) * 64];
  }
  float4v acc[4][4];
#pragma unroll
  for (int i = 0; i < 4; ++i)
#pragma unroll
    for (int j = 0; j < 4; ++j) acc[i][j] = (float4v){0.f, 0.f, 0.f, 0.f};
  for (int t = 0; t < NT; ++t) {
    __syncthreads();
#pragma unroll
    for (int q = 0; q < 4; ++q) {
      int c = q * 256 + tid; int row = c >> 3, cc = c & 7;
      short8 v; float4v f0 = av[2 * q], f1 = av[2 * q + 1];
#pragma unroll
      for (int e = 0; e < 4; ++e) { v[e] = f2bf(f0[e]); v[4 + e] = f2bf(f1[e]); }
      int off = (row * 128 + cc * 16) ^ ((row & 7) << 4);
      *reinterpret_cast<short8*>(&sA[off]) = v;
    }
#pragma unroll
    for (int u = 0; u < 4; ++u) {
      short8 v;
#pragma unroll
      for (int e = 0; e < 4; ++e) {
        int b = bv[u][e];
        v[2 * e] = f2bf((float)(b & 15) * bs + bz);
        v[2 * e + 1] = f2bf((float)((b >> 4) & 15) * bs + bz);
      }
      int off = (br * 128 + bh * 64 + u * 16) ^ ((br & 7) << 4);
      *reinterpret_cast<short8*>(&sB[off]) = v;
    }
    __syncthreads();
    if (t + 1 < NT) {
      const int tn = t + 1;
#pragma unroll
      for (int q = 0; q < 4; ++q) {
        int c = q * 256 + tid; int row = c >> 3, cc = c & 7;
        const float* p = x + (size_t)(m0 + row) * K_IN + tn * BK + cc * 8;
        av[2 * q] = *reinterpret_cast<const float4v*>(p);
        av[2 * q + 1] = *reinterpret_cast<const float4v*>(p + 4);
      }
      const int* p = wp + ((size_t)(o0 + br) * 64 + tn) * 32 + bh * 16;
#pragma unroll
      for (int q = 0; q < 4; ++q) bv[q] = *reinterpret_cast<const int4v*>(p + q * 4);
      bs = wsc[(o0 + br) * 64 + tn]; bz = wzr[(o0 + br) * 64 + tn];
    }
#pragma unroll
    for (int ks = 0; ks < 2; ++ks) {
      short8 af[4], bf[4];
      const int kb = ks * 64 + (lane >> 4) * 16;
#pragma unroll
      for (int i = 0; i < 4; ++i) {
        int row = wm * 64 + i * 16 + (lane & 15);
        af[i] = *reinterpret_cast<const short8*>(&sA[(row * 128 + kb) ^ ((row & 7) << 4)]);
      }
#pragma unroll
      for (int j = 0; j < 4; ++j) {
        int row = wo * 64 + j * 16 + (lane & 15);
        bf[j] = *reinterpret_cast<const short8*>(&sB[(row * 128 + kb) ^ ((row & 7) << 4)]);
      }
#pragma unroll
      for (int i = 0; i < 4; ++i)
#pragma unroll
        for (int j = 0; j < 4; ++j)
          acc[i][j] = __builtin_amdgcn_mfma_f32_16x16x32_bf16(af[i], bf[j], acc[i][j], 0, 0, 0);
    }
  }
#pragma unroll
  for (int j = 0; j < 4; ++j) {
    int og = o0 + wo * 64 + j * 16 + (lane & 15);
    float bb = bias[og];
#pragma unroll
    for (int i = 0; i < 4; ++i) {
      int mg = m0 + wm * 64 + i * 16 + (lane >> 4) * 4;
#pragma unroll
      for (int r = 0; r < 4; ++r)
        out[(size_t)(mg + r) * N_OUT + og] = acc[i][j][r] + bb;
    }
  }
}

extern "C" void kernel_launch(void* const* d_in, const int* in_sizes, int n_in,
                              void* d_out, int out_size, void* d_ws, size_t ws_size,
                              hipStream_t stream) {
  const float* x    = (const float*)d_in[0];
  const int* wp     = (const int*)d_in[1];
  const float* wsc  = (const float*)d_in[2];
  const float* wzr  = (const float*)d_in[3];
  const float* bias = (const float*)d_in[4];
  float* out = (float*)d_out;

  const size_t xb_bytes = (size_t)M_TOTAL * K_IN * 2;  // 67108864
  const size_t wb_bytes = (size_t)N_OUT * K_IN * 2;    // 33554432

  if (ws_size >= xb_bytes + wb_bytes) {
    short* xb = (short*)d_ws;
    short* wb = (short*)((char*)d_ws + xb_bytes);
    cvt_x_kernel<<<2048, 256, 0, stream>>>(x, xb, (int)((size_t)M_TOTAL * K_IN / 8));
    deq_w_kernel<<<2048, 256, 0, stream>>>(wp, wsc, wzr, wb);
    dim3 grid(N_OUT / BN, M_TOTAL / BM);
    qgemm_kernel<<<grid, dim3(256), 0, stream>>>(xb, wb, bias, out);
  } else {
    dim3 grid(N_OUT / BN, M_TOTAL / BM);
    qlin_fused_kernel<<<grid, dim3(256), 0, stream>>>(x, wp, wsc, wzr, bias, out);
  }
}

// Round 3
// 275.824 us; speedup vs baseline: 1.8723x; 1.2173x over previous
//
#include <hip/hip_runtime.h>
#include <hip/hip_bf16.h>

// QuantizedLinear: out[M,O] = x[M,K] @ W[O,K]^T + bias, W 4-bit group-quant (G=64)
// M=8192, O=4096, K=4096.
// Round 3: 256x256 8-phase schedule (T2 swizzle + T3 phases + T4 counted vmcnt + T5 setprio)
// on top of the round-2 prepasses (x->bf16, W dequant->bf16).

typedef short short8 __attribute__((ext_vector_type(8)));
typedef float float4v __attribute__((ext_vector_type(4)));
typedef int int4v __attribute__((ext_vector_type(4)));

#define M_TOTAL 8192
#define N_OUT 4096
#define K_IN 4096
#define BM 256
#define BN 256
#define BK 64
#define NT (K_IN / BK) // 64 K-tiles

// RTNE float->bf16
__device__ __forceinline__ short f2bf(float f) {
  unsigned int u = __builtin_bit_cast(unsigned int, f);
  unsigned int r = (u + 0x7fffu + ((u >> 16) & 1u)) >> 16;
  return (short)(unsigned short)r;
}

__device__ __forceinline__ void gload_lds16(const void* g, void* l) {
  __builtin_amdgcn_global_load_lds(
      (const __attribute__((address_space(1))) void*)g,
      (__attribute__((address_space(3))) void*)l, 16, 0, 0);
}

// ---------------- prepass 1: x f32 -> bf16 ----------------
__global__ __launch_bounds__(256)
void cvt_x_kernel(const float* __restrict__ x, short* __restrict__ xb, int n8) {
  int i = blockIdx.x * blockDim.x + threadIdx.x;
  int stride = gridDim.x * blockDim.x;
  for (; i < n8; i += stride) {
    const float* p = x + (size_t)i * 8;
    float4v f0 = *reinterpret_cast<const float4v*>(p);
    float4v f1 = *reinterpret_cast<const float4v*>(p + 4);
    short8 v;
#pragma unroll
    for (int e = 0; e < 4; ++e) { v[e] = f2bf(f0[e]); v[4 + e] = f2bf(f1[e]); }
    *reinterpret_cast<short8*>(xb + (size_t)i * 8) = v;
  }
}

// ---------------- prepass 2: W 4-bit -> bf16 [O][K] ----------------
__global__ __launch_bounds__(256)
void deq_w_kernel(const int* __restrict__ wp, const float* __restrict__ wsc,
                  const float* __restrict__ wzr, short* __restrict__ wb) {
  int t = blockIdx.x * blockDim.x + threadIdx.x; // 0..524287
  int g = t >> 1, h = t & 1;
  float s = wsc[g], z = wzr[g];
  const int* p = wp + (size_t)g * 32 + h * 16;
  int4v b[4];
#pragma unroll
  for (int u = 0; u < 4; ++u) b[u] = *reinterpret_cast<const int4v*>(p + u * 4);
  short* o = wb + (size_t)t * 32;
#pragma unroll
  for (int u = 0; u < 4; ++u) {
    short8 v;
#pragma unroll
    for (int e = 0; e < 4; ++e) {
      int bb = b[u][e];
      v[2 * e]     = f2bf((float)(bb & 15) * s + z);
      v[2 * e + 1] = f2bf((float)((bb >> 4) & 15) * s + z);
    }
    *reinterpret_cast<short8*>(o + u * 8) = v;
  }
}

// ---------------- main GEMM: 256x256 tile, 8-phase, 8 waves ----------------
// LDS (128 KiB): buf[2] x { A: [mg 2][wh 2][64 r][64 c bf16]  B: [ng 2][128 r][64 c] }
// Swizzle: 16B slot s of row r holds logical k-slot s ^ (r&7); gload_lds writes
// linearly, so the GLOBAL source col per lane is pre-permuted: kslot = (l&7)^((l>>3)&7).
// Chunks per K-tile: Atop(mg0) Bright(ng1) Bleft(ng0) Abot(mg1), 16KB each
// (2 gload_lds x 8 waves). Quadrants: Q1(mg0,ng1) Q2(mg0,ng0) Q3(mg1,ng0) Q4(mg1,ng1;
// br regs reused from Q1). Issue phase > last-read phase for every chunk (race-free);
// vmcnt(6) at ph4/ph8 guarantees next K-tile fully landed.

#define MFMA_BF16 __builtin_amdgcn_mfma_f32_16x16x32_bf16
#define BAR() __builtin_amdgcn_s_barrier()
#define PRIO1() __builtin_amdgcn_s_setprio(1)
#define PRIO0() __builtin_amdgcn_s_setprio(0)
#define VMCNT6() asm volatile("s_waitcnt vmcnt(6)" ::: "memory")
#define VMCNT0() asm volatile("s_waitcnt vmcnt(0)" ::: "memory")

__global__ __launch_bounds__(512, 2)
void qgemm8_kernel(const short* __restrict__ A, const short* __restrict__ B,
                   const float* __restrict__ bias, float* __restrict__ out) {
  __shared__ __align__(16) char L[131072];

  const int tid  = threadIdx.x;
  const int lane = tid & 63;
  const int w    = tid >> 6;  // 0..7
  const int wm   = w >> 2;    // 0..1  (M half)
  const int wn   = w & 3;     // 0..3  (N quarter)

  const int m0 = blockIdx.y * BM;
  const int o0 = blockIdx.x * BN;

  // ---- staging precompute (per thread) ----
  const int kslot = (lane & 7) ^ ((lane >> 3) & 7);     // pre-swizzled global k-slot
  const int R0 = w * 16 + (lane >> 3);                  // piece row q=0 (0..127)
  const int R1 = R0 + 8;                                // piece row q=1
  const short* pA0 = A + (size_t)(m0 + (R0 >> 6) * 128 + (R0 & 63)) * K_IN + kslot * 8;
  const short* pA1 = A + (size_t)(m0 + (R1 >> 6) * 128 + (R1 & 63)) * K_IN + kslot * 8;
  const short* pB0 = B + (size_t)(o0 + (R0 >> 5) * 64 + (R0 & 31)) * K_IN + kslot * 8;
  const short* pB1 = B + (size_t)(o0 + (R1 >> 5) * 64 + (R1 & 31)) * K_IN + kslot * 8;
  const int ldsp0 = w * 2048 + lane * 16;               // linear LDS piece dest (bytes)
  const int ldsp1 = ldsp0 + 1024;

#define STAGE_A(buf, mg, t) do { \
    gload_lds16(pA0 + (size_t)(mg) * 64 * K_IN + (t) * 64, &L[(buf) * 65536 + (mg) * 16384 + ldsp0]); \
    gload_lds16(pA1 + (size_t)(mg) * 64 * K_IN + (t) * 64, &L[(buf) * 65536 + (mg) * 16384 + ldsp1]); \
  } while (0)
#define STAGE_B(buf, ng, t) do { \
    gload_lds16(pB0 + (size_t)(ng) * 32 * K_IN + (t) * 64, &L[(buf) * 65536 + 32768 + (ng) * 16384 + ldsp0]); \
    gload_lds16(pB1 + (size_t)(ng) * 32 * K_IN + (t) * 64, &L[(buf) * 65536 + 32768 + (ng) * 16384 + ldsp1]); \
  } while (0)

  // ---- fragment-read precompute ----
  const int l15   = lane & 15;
  const int abase = wm * 8192 + l15 * 128;          // within A region [wh][64r][128B]
  const int bbase = 32768 + wn * 4096 + l15 * 128;  // within B region [128r][128B]
  const int sl0 = (((lane >> 4) + 0) ^ (lane & 7)) * 16; // swizzled 16B slot, ks=0
  const int sl1 = (((lane >> 4) + 4) ^ (lane & 7)) * 16; // ks=1

  short8 a[8], bl[4], br[4];

#define RD_A(buf, mg) do { \
    _Pragma("unroll") for (int mf = 0; mf < 4; ++mf) { \
      a[mf * 2 + 0] = *reinterpret_cast<const short8*>(&L[(buf) * 65536 + (mg) * 16384 + abase + mf * 2048 + sl0]); \
      a[mf * 2 + 1] = *reinterpret_cast<const short8*>(&L[(buf) * 65536 + (mg) * 16384 + abase + mf * 2048 + sl1]); \
    } } while (0)
#define RD_B(dst, buf, ng) do { \
    _Pragma("unroll") for (int nf = 0; nf < 2; ++nf) { \
      dst[nf * 2 + 0] = *reinterpret_cast<const short8*>(&L[(buf) * 65536 + (ng) * 16384 + bbase + nf * 2048 + sl0]); \
      dst[nf * 2 + 1] = *reinterpret_cast<const short8*>(&L[(buf) * 65536 + (ng) * 16384 + bbase + nf * 2048 + sl1]); \
    } } while (0)

  float4v acc[8][4];
#pragma unroll
  for (int i = 0; i < 8; ++i)
#pragma unroll
    for (int j = 0; j < 4; ++j) acc[i][j] = (float4v){0.f, 0.f, 0.f, 0.f};

#define DO_QUAD(mg, ng, bb_) do { \
    _Pragma("unroll") for (int ks = 0; ks < 2; ++ks) \
    _Pragma("unroll") for (int mf = 0; mf < 4; ++mf) \
    _Pragma("unroll") for (int nf = 0; nf < 2; ++nf) \
      acc[(mg) * 4 + mf][(ng) * 2 + nf] = \
        MFMA_BF16(a[mf * 2 + ks], bb_[nf * 2 + ks], acc[(mg) * 4 + mf][(ng) * 2 + nf], 0, 0, 0); \
  } while (0)

  // ---- prologue: kt0 (4 chunks, buf0) + kt1 (3 chunks, buf1) ----
  STAGE_A(0, 0, 0); STAGE_B(0, 1, 0); STAGE_B(0, 0, 0); STAGE_A(0, 1, 0);
  STAGE_A(1, 0, 1); STAGE_B(1, 1, 1); STAGE_B(1, 0, 1);
  VMCNT6();  // oldest 4 chunks (= all of kt0) landed
  BAR();

  // ---- main loop: iterations 0..30 compute kt=2i (buf0), kt+1 (buf1) ----
  for (int i = 0; i < NT / 2 - 1; ++i) {
    const int t2 = 2 * i + 2, t3 = 2 * i + 3;
    // ph1: Q1(kt) | stage kt+1.Abot -> buf1
    RD_A(0, 0); RD_B(br, 0, 1);
    STAGE_A(1, 1, t3 - 2);
    BAR(); PRIO1(); DO_QUAD(0, 1, br); PRIO0(); BAR();
    // ph2: Q2(kt) | stage kt+2.Atop -> buf0 (Atop last read ph1)
    RD_B(bl, 0, 0);
    STAGE_A(0, 0, t2);
    BAR(); PRIO1(); DO_QUAD(0, 0, bl); PRIO0(); BAR();
    // ph3: Q3(kt) | stage kt+2.Bright -> buf0 (Bright last read ph1; regs reused)
    RD_A(0, 1);
    STAGE_B(0, 1, t2);
    BAR(); PRIO1(); DO_QUAD(1, 0, bl); PRIO0(); BAR();
    // ph4: Q4(kt, br reused) | stage kt+2.Bleft -> buf0 (last read ph2) | vmcnt(6)
    STAGE_B(0, 0, t2);
    VMCNT6();  // guarantees kt+1 fully landed
    BAR(); PRIO1(); DO_QUAD(1, 1, br); PRIO0(); BAR();
    // ph5: Q1(kt+1) | stage kt+2.Abot -> buf0 (last read ph3)
    RD_A(1, 0); RD_B(br, 1, 1);
    STAGE_A(0, 1, t2);
    BAR(); PRIO1(); DO_QUAD(0, 1, br); PRIO0(); BAR();
    // ph6: Q2(kt+1) | stage kt+3.Atop -> buf1 (Atop last read ph5)
    RD_B(bl, 1, 0);
    STAGE_A(1, 0, t3);
    BAR(); PRIO1(); DO_QUAD(0, 0, bl); PRIO0(); BAR();
    // ph7: Q3(kt+1) | stage kt+3.Bright -> buf1
    RD_A(1, 1);
    STAGE_B(1, 1, t3);
    BAR(); PRIO1(); DO_QUAD(1, 0, bl); PRIO0(); BAR();
    // ph8: Q4(kt+1) | stage kt+3.Bleft -> buf1 (last read ph6) | vmcnt(6)
    STAGE_B(1, 0, t3);
    VMCNT6();  // guarantees kt+2 fully landed
    BAR(); PRIO1(); DO_QUAD(1, 1, br); PRIO0(); BAR();
  }

  // ---- epilogue: kt=62 (buf0), kt=63 (buf1) ----
  RD_A(0, 0); RD_B(br, 0, 1);
  STAGE_A(1, 1, 63);  // kt63.Abot
  BAR(); PRIO1(); DO_QUAD(0, 1, br); PRIO0(); BAR();
  RD_B(bl, 0, 0);
  BAR(); PRIO1(); DO_QUAD(0, 0, bl); PRIO0(); BAR();
  RD_A(0, 1);
  BAR(); PRIO1(); DO_QUAD(1, 0, bl); PRIO0(); BAR();
  VMCNT0();  // drain: kt63 fully landed
  BAR(); PRIO1(); DO_QUAD(1, 1, br); PRIO0(); BAR();
  RD_A(1, 0); RD_B(br, 1, 1);
  BAR(); PRIO1(); DO_QUAD(0, 1, br); PRIO0(); BAR();
  RD_B(bl, 1, 0);
  BAR(); PRIO1(); DO_QUAD(0, 0, bl); PRIO0(); BAR();
  RD_A(1, 1);
  BAR(); PRIO1(); DO_QUAD(1, 0, bl); PRIO0(); BAR();
  PRIO1(); DO_QUAD(1, 1, br); PRIO0();

  // ---- C write: col = o0 + wn*64 + nf*16 + (lane&15); row = m0 + wm*128 + mf*16 + (lane>>4)*4 + r
#pragma unroll
  for (int nf = 0; nf < 4; ++nf) {
    const int col = o0 + wn * 64 + nf * 16 + l15;
    const float bb = bias[col];
#pragma unroll
    for (int mf = 0; mf < 8; ++mf) {
      const int rowb = m0 + wm * 128 + mf * 16 + (lane >> 4) * 4;
#pragma unroll
      for (int r = 0; r < 4; ++r)
        out[(size_t)(rowb + r) * N_OUT + col] = acc[mf][nf][r] + bb;
    }
  }
}

extern "C" void kernel_launch(void* const* d_in, const int* in_sizes, int n_in,
                              void* d_out, int out_size, void* d_ws, size_t ws_size,
                              hipStream_t stream) {
  const float* x    = (const float*)d_in[0];
  const int* wp     = (const int*)d_in[1];
  const float* wsc  = (const float*)d_in[2];
  const float* wzr  = (const float*)d_in[3];
  const float* bias = (const float*)d_in[4];
  float* out = (float*)d_out;

  const size_t xb_bytes = (size_t)M_TOTAL * K_IN * 2;
  short* xb = (short*)d_ws;
  short* wb = (short*)((char*)d_ws + xb_bytes);

  cvt_x_kernel<<<2048, 256, 0, stream>>>(x, xb, (int)((size_t)M_TOTAL * K_IN / 8));
  deq_w_kernel<<<2048, 256, 0, stream>>>(wp, wsc, wzr, wb);
  dim3 grid(N_OUT / BN, M_TOTAL / BM); // (16, 32)
  qgemm8_kernel<<<grid, dim3(512), 0, stream>>>(xb, wb, bias, out);
}